// Round 6
// baseline (218.135 us; speedup 1.0000x reference)
//
#include <hip/hip_runtime.h>

#define DT 0.03f
#define SEQ_LEN 30
#define D_STEER (0.4f * 0.03f)

#define BT 64            // threads per block (one wave) == rows per tile
#define PAD 31           // float4 stride per row in LDS (30 + 1 pad)

typedef float f32x2 __attribute__((ext_vector_type(2)));
typedef float f32x4 __attribute__((ext_vector_type(4)));

__global__ __launch_bounds__(64) void ccdec_kernel(
    const float* __restrict__ z,
    const float* __restrict__ init_state,
    float* __restrict__ out,
    int B)
{
    __shared__ f32x4 lds[BT * PAD];   // 31744 B -> 5 blocks/CU (LDS-bound)

    const int tid    = threadIdx.x;
    const int ntiles = (B + BT - 1) / BT;

    int tile = blockIdx.x;
    if (tile >= ntiles) return;

    // ---- prefetch inputs for the first tile ----
    int b  = tile * BT + tid;
    int bb = (b < B) ? b : (B - 1);
    f32x2 zv  = *(reinterpret_cast<const f32x2*>(z) + (size_t)bb);
    const f32x2* stp = reinterpret_cast<const f32x2*>(init_state) + 3ull * (size_t)bb;
    f32x2 s01 = stp[0];
    f32x2 s23 = stp[1];
    f32x2 s45 = stp[2];

    for (; tile < ntiles; tile += gridDim.x) {
        // ---- unpack current tile's inputs ----
        float x   = s01.x;
        float y   = s01.y;
        float psi = s23.x;
        float v   = s23.y;
        float last_st = s45.y;   // init_state[:,5]

        // ---- steering / pedal preamble (mirror clip_by_tensor semantics) ----
        float steering = zv.y * 0.5f;
        float tmin = last_st - D_STEER;
        float tmax = last_st + D_STEER;
        float r = (steering > tmin) ? steering : ((steering < tmin) ? tmin : 0.0f);
        r = (r <= tmax) ? r : tmax;
        steering = fminf(fmaxf(r, -0.5f), 0.5f);

        float pedal = zv.x * 2.5f;
        float beta  = fminf(fmaxf(steering, -0.5f), 0.5f);
        float a_t   = fminf(fmaxf(pedal, -2.5f), 2.5f);
        float tan_beta = __tanf(beta);
        float dpsi_k   = tan_beta * (1.0f / 2.5f) * DT;
        float adt      = a_t * DT;

        // ---- compute all 30 steps into LDS (full rows) ----
        #pragma unroll
        for (int t = 0; t < SEQ_LEN; ++t) {
            float v1 = fminf(fmaxf(v + adt, 0.0f), 10.0f);
            psi = v * dpsi_k + psi;          // uses OLD v
            float s, c;
            __sincosf(psi, &s, &c);
            x = v1 * c * DT + x;
            y = v1 * s * DT + y;
            v = v1;
            f32x4 o; o.x = x; o.y = y; o.z = psi; o.w = v;
            lds[tid * PAD + t] = o;
        }
        __syncthreads();

        // ---- issue next tile's input loads BEFORE the store burst ----
        // (HBM load latency hides under the 30 wave-wide stores below)
        int ntile = tile + gridDim.x;
        if (ntile < ntiles) {
            int nb  = ntile * BT + tid;
            int nbb = (nb < B) ? nb : (B - 1);
            zv  = *(reinterpret_cast<const f32x2*>(z) + (size_t)nbb);
            const f32x2* nstp = reinterpret_cast<const f32x2*>(init_state) + 3ull * (size_t)nbb;
            s01 = nstp[0];
            s23 = nstp[1];
            s45 = nstp[2];
        }

        // ---- stream tile out flat: every wave store = 16 full aligned lines ----
        if ((tile + 1) * BT <= B) {
            f32x4* outp4 = reinterpret_cast<f32x4*>(out) + (size_t)tile * BT * SEQ_LEN;
            int rr = tid / SEQ_LEN;          // incremental div: f = tid + m*64
            int jj = tid - rr * SEQ_LEN;
            #pragma unroll
            for (int m = 0; m < SEQ_LEN; ++m) {
                outp4[tid + m * BT] = lds[rr * PAD + jj];
                // advance flat index by 64: 64 = 2*30 + 4
                rr += 2; jj += 4;
                if (jj >= SEQ_LEN) { jj -= SEQ_LEN; rr += 1; }
            }
        } else {
            // partial tile: guarded per-row stores (correctness only)
            int wb = tile * BT + tid;
            if (wb < B) {
                f32x4* outp = reinterpret_cast<f32x4*>(out) + (size_t)wb * SEQ_LEN;
                #pragma unroll
                for (int t = 0; t < SEQ_LEN; ++t) outp[t] = lds[tid * PAD + t];
            }
        }
        __syncthreads();   // LDS reused next iteration
    }
}

extern "C" void kernel_launch(void* const* d_in, const int* in_sizes, int n_in,
                              void* d_out, int out_size, void* d_ws, size_t ws_size,
                              hipStream_t stream)
{
    const float* z          = (const float*)d_in[0];   // (B, 2) f32
    const float* init_state = (const float*)d_in[1];   // (B, 6) f32
    float* out = (float*)d_out;                        // (B, 30, 4) f32

    int B = in_sizes[0] / 2;
    int ntiles = (B + BT - 1) / BT;
    int grid = 256 * 5;                 // 5 resident 1-wave blocks per CU
    if (grid > ntiles) grid = ntiles;
    ccdec_kernel<<<grid, BT, 0, stream>>>(z, init_state, out, B);
}